// Round 7
// baseline (118.593 us; speedup 1.0000x reference)
//
#include <hip/hip_runtime.h>

#define IC 64
#define OC 64
#define NSH 45
#define BATCH 2048
#define PI_F 3.14159265358979323846f
#define WF2_FLOATS (64 * 64 * 48)   // wf2[i][o][c48] = 786,432 B

typedef float f4  __attribute__((ext_vector_type(4), aligned(4)));   // global (4B-aligned)
typedef float f4s __attribute__((ext_vector_type(4), aligned(16)));  // LDS (16B-aligned)

// ---------------- weight fold: wf2[i][o][c48] = w[o][i][ls[c]/2] * sqrt(pi/(2l+1))
__global__ __launch_bounds__(256) void fold2_kernel(const float* __restrict__ w,
                                                    const int* __restrict__ ls,
                                                    float* __restrict__ wf) {
    int t = blockIdx.x * 256 + threadIdx.x;    // [0, 49152)
    int cq = t % 12;
    int io = t / 12;                           // [0, 4096)
    int o  = io & 63;
    int i  = io >> 6;                          // input channel
    f4 v;
#pragma unroll
    for (int cc = 0; cc < 4; ++cc) {
        int c = cq * 4 + cc;
        float r = 0.0f;
        if (c < NSH) {
            int l = ls[c];
            r = w[((size_t)o * IC + i) * 5 + (l >> 1)] *
                sqrtf(PI_F / (2.0f * (float)l + 1.0f));
        }
        v[cc] = r;
    }
    *(f4*)(wf + ((size_t)i * OC + o) * 48 + cq * 4) = v;   // 16B-aligned
}

// ---------------- main kernel
// 192 blocks = 16 bt (128 b) x 12 cg (c-quad, overlap trick at cg=11).
// Block 256 thr = 4 waves; wave = o-slice of 16. Thread tile 8b x 4o x 4c.
// LDS 96 KB: x[i16][b128][c4] + w[i16][o64][c4], double-buffered i-chunks.
// Hot loop: pure ds_read + FMA (single lgkm source -> counted lgkmcnt);
// global loads for chunk k+1 issued before compute of k (T14), ds_write after.
__global__ __launch_bounds__(256, 1) void sph_main(const float* __restrict__ x,
                                                   const float* __restrict__ wf,
                                                   float* __restrict__ out) {
    __shared__ f4s xs[2][16][128];   // 64 KB
    __shared__ f4s wl[2][16][64];    // 32 KB

    // XCD swizzle: all 12 cg-blocks of a bt share one XCD's L2 (x-line sharing:
    // the 12 c-quads of each 180B x-row are consumed from one L2).
    int bid = blockIdx.x;            // [0,192)
    int xcd = bid & 7;
    int r   = bid >> 3;              // [0,24)
    int hi  = (r >= 12);
    int bt  = xcd * 2 + hi;          // [0,16)
    int cg  = r - hi * 12;           // [0,12)

    int c0 = (cg < 11) ? cg * 4 : 41;   // overlapping last quad covers 0..44
    int b0 = bt * 128;

    int tid  = threadIdx.x;
    int wv   = tid >> 6;
    int lane = tid & 63;
    int bg   = lane >> 2;            // [0,16)
    int og   = lane & 3;             // [0,4)
    int ow   = wv * 16 + og * 4;     // thread's o-base (4 consecutive o)

    float acc[8][4][4];
#pragma unroll
    for (int bb = 0; bb < 8; ++bb)
#pragma unroll
        for (int oo = 0; oo < 4; ++oo)
#pragma unroll
            for (int cc = 0; cc < 4; ++cc) acc[bb][oo][cc] = 0.0f;

    f4 stgx[8], stgw[4];

    // stage-load chunk k (global -> regs): x 8 slots, w 4 slots per thread
#define SLOAD(k)                                                              \
    {                                                                         \
        _Pragma("unroll") for (int j = 0; j < 8; ++j) {                       \
            int s = tid + 256 * j;                                            \
            int il = s >> 7, b = s & 127;                                     \
            stgx[j] = *(const f4*)(x + ((size_t)(b0 + b) * IC + (k) * 16 + il) * NSH + c0); \
        }                                                                     \
        _Pragma("unroll") for (int j = 0; j < 4; ++j) {                       \
            int s = tid + 256 * j;                                            \
            int il = s >> 6, o = s & 63;                                      \
            stgw[j] = *(const f4*)(wf + ((size_t)((k) * 16 + il) * OC + o) * 48 + c0); \
        }                                                                     \
    }
#define SWRITE(nb)                                                            \
    {                                                                         \
        _Pragma("unroll") for (int j = 0; j < 8; ++j) {                       \
            int s = tid + 256 * j;                                            \
            xs[nb][s >> 7][s & 127] = (f4s)stgx[j];                           \
        }                                                                     \
        _Pragma("unroll") for (int j = 0; j < 4; ++j) {                       \
            int s = tid + 256 * j;                                            \
            wl[nb][s >> 6][s & 63] = (f4s)stgw[j];                            \
        }                                                                     \
    }

    SLOAD(0);
    SWRITE(0);
    __syncthreads();

#pragma unroll 1
    for (int k = 0; k < 4; ++k) {
        if (k < 3) SLOAD(k + 1);           // T14: issue next chunk's loads early
        const int cb = k & 1;
#pragma unroll 4
        for (int i = 0; i < 16; ++i) {
            f4s wq[4];
#pragma unroll
            for (int oo = 0; oo < 4; ++oo) wq[oo] = wl[cb][i][ow + oo];
#pragma unroll
            for (int bb = 0; bb < 8; ++bb) {
                f4s xq = xs[cb][i][bg + 16 * bb];
#pragma unroll
                for (int oo = 0; oo < 4; ++oo)
#pragma unroll
                    for (int cc = 0; cc < 4; ++cc)
                        acc[bb][oo][cc] = fmaf(xq[cc], wq[oo][cc], acc[bb][oo][cc]);
            }
        }
        if (k < 3) {
            SWRITE((k + 1) & 1);           // vmcnt wait lands here, under the FMAs
            __syncthreads();
        }
    }

    // store: 32 x dwordx4 per thread; cg10/11 overlap rows carry identical values
    float* op = out + ((size_t)(b0 + bg) * OC + ow) * NSH + c0;
#pragma unroll
    for (int bb = 0; bb < 8; ++bb)
#pragma unroll
        for (int oo = 0; oo < 4; ++oo) {
            f4 rr;
            rr[0] = acc[bb][oo][0]; rr[1] = acc[bb][oo][1];
            rr[2] = acc[bb][oo][2]; rr[3] = acc[bb][oo][3];
            *(f4*)(op + (size_t)bb * 16 * OC * NSH + (size_t)oo * NSH) = rr;
        }
}

// ---------------- fallback (tiny ws): correct but unoptimized
__global__ __launch_bounds__(128) void sph_raw(const float* __restrict__ x,
                                               const float* __restrict__ w,
                                               const int* __restrict__ ls,
                                               float* __restrict__ out) {
    int t = blockIdx.x * 128 + threadIdx.x;    // one thread per (b, o)
    if (t >= BATCH * OC) return;
    int o = t & 63;
    int b = t >> 6;
    float res[NSH];
#pragma unroll 1
    for (int c = 0; c < NSH; ++c) res[c] = 0.0f;
#pragma unroll 1
    for (int i = 0; i < IC; ++i) {
        const float* xr = x + ((size_t)b * IC + i) * NSH;
        const float* wr = w + ((size_t)o * IC + i) * 5;
        float wl5[5];
#pragma unroll
        for (int l2 = 0; l2 < 5; ++l2) wl5[l2] = wr[l2];
#pragma unroll 1
        for (int c = 0; c < NSH; ++c) res[c] = fmaf(xr[c], wl5[ls[c] >> 1], res[c]);
    }
#pragma unroll 1
    for (int c = 0; c < NSH; ++c) {
        float sc = sqrtf(PI_F / (2.0f * (float)ls[c] + 1.0f));
        out[((size_t)b * OC + o) * NSH + c] = res[c] * sc;
    }
}

extern "C" void kernel_launch(void* const* d_in, const int* in_sizes, int n_in,
                              void* d_out, int out_size, void* d_ws, size_t ws_size,
                              hipStream_t stream) {
    const float* x  = (const float*)d_in[0];
    const float* wt = (const float*)d_in[1];
    const int*   ls = (const int*)d_in[2];
    float* out = (float*)d_out;

    if (ws_size >= (size_t)WF2_FLOATS * sizeof(float)) {
        float* wf = (float*)d_ws;
        fold2_kernel<<<192, 256, 0, stream>>>(wt, ls, wf);
        sph_main<<<192, 256, 0, stream>>>(x, wf, out);
    } else {
        sph_raw<<<(BATCH * OC + 127) / 128, 128, 0, stream>>>(x, wt, ls, out);
    }
}